// Round 5
// baseline (418.246 us; speedup 1.0000x reference)
//
#include <hip/hip_runtime.h>
#include <math.h>

#define B 128
#define D 512
#define S 512
#define TOPK 10

typedef short bf16x8 __attribute__((ext_vector_type(8)));
typedef unsigned short u16x8 __attribute__((ext_vector_type(8)));
typedef float f32x4 __attribute__((ext_vector_type(4)));

// -------- workspace layout (floats) --------
// g      @ 0        [65536]     (zeroed with score in one pass)
// score  @ 65536    [65536]
// gterm  @ 131072   [65536]     (written directly, no zero needed)
// C1     @ 196608   [262144]
// w1tsw  @ 458752   [524288]    (ushort [2 rp][32 ts][4 kc][256 m][16], slot-swizzled)
// peh    @ 983040   [262144]    (512 s x 1024 f bf16, row-major)
// pel    @ 1245184  [262144]
// total 1507328 floats = 5.75 MB
//
// slot swizzle: row m's hi 8 ushorts live at +((m>>2)&1)*8, lo at the other slot.
// quad(m,h) = (2*(m&3) + (h ^ ((m>>2)&1))) & 7 sweeps all 8 LDS bank-quads over any
// 8 consecutive rows -> b128 fragment reads/writes hit the 8-cycle floor.

// ---------------- split fp32 -> (hi bf16 RNE, lo bf16 RZ), packed ----------------
__device__ __forceinline__ unsigned splitf(float f) {
    unsigned u = __float_as_uint(f);
    unsigned rb = u + 0x7FFFu + ((u >> 16) & 1u);  // RNE to bf16
    float hf = __uint_as_float(rb & 0xFFFF0000u);
    unsigned u2 = __float_as_uint(f - hf);  // exact residual
    return (rb >> 16) | (u2 & 0xFFFF0000u);
}

// element-offset (ushorts) of row-base of (d,k) in w1tsw; hi slot = +((d>>2)&1)*8
__device__ __forceinline__ size_t w1t_base(int d, int k) {
    return (size_t)(((d >> 8) * 32 + (k >> 5)) * 4 + ((k >> 3) & 3)) * 4096 +
           (size_t)(d & 255) * 16 + (k & 7);
}

// ---------------- zero g+score (128K floats) ----------------
__global__ void zero_kernel(float* __restrict__ p) {
    p[blockIdx.x * 256 + threadIdx.x] = 0.0f;
}

// ---------------- fused stage 1: transpose+mean | pe | w1split ----------------
// blocks [0,8192): transpose 64x64 tile; [8192,8704): pe row; [8704,8768): w1split
__global__ __launch_bounds__(256) void fused_stage1(
    const float* __restrict__ x, float* __restrict__ feat, float* __restrict__ g,
    ushort* __restrict__ peh, ushort* __restrict__ pel,
    const float* __restrict__ w1, ushort* __restrict__ w1tsw) {
    __shared__ float tile[64 * 65];  // addr(d,s) = d + s*65 (2-way aliasing = free)
    int bid = (int)blockIdx.x;
    int t = threadIdx.x;

    if (bid < 8192) {
        // ---- transpose + mean: feat[b,s,d] = x[b,d,s]; g[b,d] += atomic partials ----
        int b = bid >> 6;
        int s0 = (bid & 7) * 64, d0 = ((bid >> 3) & 7) * 64;
        int ty = t >> 4, tx = t & 15;
        const float4* x4 = (const float4*)(x + (size_t)b * D * S);
        float psum[4];
#pragma unroll
        for (int q = 0; q < 4; ++q) {
            int d = ty + 16 * q;
            float4 v = x4[(size_t)(d0 + d) * (S / 4) + (s0 >> 2) + tx];
            tile[d + (4 * tx + 0) * 65] = v.x;
            tile[d + (4 * tx + 1) * 65] = v.y;
            tile[d + (4 * tx + 2) * 65] = v.z;
            tile[d + (4 * tx + 3) * 65] = v.w;
            float sm = (v.x + v.y) + (v.z + v.w);
#pragma unroll
            for (int off = 8; off; off >>= 1) sm += __shfl_down(sm, off, 16);
            psum[q] = sm;
        }
        if (tx == 0) {
#pragma unroll
            for (int q = 0; q < 4; ++q)
                atomicAdd(&g[b * D + d0 + ty + 16 * q], psum[q] * (1.0f / S));
        }
        __syncthreads();
        float4* f4 = (float4*)(feat + (size_t)b * S * D);
#pragma unroll
        for (int q = 0; q < 4; ++q) {
            int s = ty + 16 * q;
            float4 o;
            o.x = tile[(4 * tx + 0) + s * 65];
            o.y = tile[(4 * tx + 1) + s * 65];
            o.z = tile[(4 * tx + 2) + s * 65];
            o.w = tile[(4 * tx + 3) + s * 65];
            f4[(size_t)(s0 + s) * (D / 4) + (d0 >> 2) + tx] = o;
        }
    } else if (bid < 8704) {
        // ---- pe precompute + split: pe[s][f], f=2i sin / 2i+1 cos ----
        int s = bid - 8192;
#pragma unroll
        for (int q = 0; q < 2; ++q) {
            int i = t + 256 * q;  // 0..511
            float ei = expf((float)(2 * i) * -0.0089944730195f);  // -ln(10000)/1024 * 2i
            float ang = (float)s * ei;
            float sv = sinf(ang), cv = cosf(ang);
            unsigned ps = splitf(sv), pc = splitf(cv);
            size_t base = (size_t)s * 1024 + 2 * i;
            peh[base] = (ushort)(ps & 0xFFFFu);
            peh[base + 1] = (ushort)(pc & 0xFFFFu);
            pel[base] = (ushort)(ps >> 16);
            pel[base + 1] = (ushort)(pc >> 16);
        }
    } else {
        // ---- w1 split+transpose into tiled chunk-major slot-swizzled layout ----
        int id2 = bid - 8704;  // 0..63
        int rp = id2 & 1, tt = id2 >> 1;
        int m = t;
        int d = rp * 256 + m;
        int hs = (m >> 2) & 1;
        ushort* outp = w1tsw + (size_t)(rp * 32 + tt) * 16384 + (size_t)m * 16;
#pragma unroll
        for (int c = 0; c < 4; ++c) {
            u16x8 hi, lo;
#pragma unroll
            for (int j = 0; j < 8; ++j) {
                unsigned p = splitf(w1[(size_t)(tt * 32 + c * 8 + j) * D + d]);
                hi[j] = (ushort)(p & 0xFFFFu);
                lo[j] = (ushort)(p >> 16);
            }
            *(u16x8*)(outp + c * 4096 + hs * 8) = hi;
            *(u16x8*)(outp + c * 4096 + (hs ^ 1) * 8) = lo;
        }
    }
}

// ---------------- fused stage 2: gterm (no atomics) | c1 ----------------
#define CP 40
// blocks [0,256): gterm for (b, half); [256,320): c1 64x64 tile
__global__ __launch_bounds__(256) void fused_stage2(
    const float* __restrict__ g, const float* __restrict__ w1, float* __restrict__ gterm,
    const ushort* __restrict__ peh, const ushort* __restrict__ pel,
    const ushort* __restrict__ w1tsw, const float* __restrict__ b1,
    float* __restrict__ C1) {
    __shared__ short smemS[4 * 64 * CP];  // c1: 4 arrays; gterm: 512 floats at front
    int bid = (int)blockIdx.x;
    int t = threadIdx.x;

    if (bid < 256) {
        // ---- gterm[b,d] = sum_k g[b,k] * w1[D+k, d], direct write ----
        int b = bid >> 1, half = bid & 1;
        float* gs = (float*)smemS;
        gs[t] = g[b * D + t];
        gs[t + 256] = g[b * D + 256 + t];
        __syncthreads();
        int d = half * 256 + t;
        float a0 = 0.f, a1 = 0.f, a2 = 0.f, a3 = 0.f;
        for (int k = 0; k < 512; k += 4) {
            a0 += gs[k + 0] * w1[(size_t)(D + k + 0) * D + d];
            a1 += gs[k + 1] * w1[(size_t)(D + k + 1) * D + d];
            a2 += gs[k + 2] * w1[(size_t)(D + k + 2) * D + d];
            a3 += gs[k + 3] * w1[(size_t)(D + k + 3) * D + d];
        }
        gterm[b * D + d] = (a0 + a1) + (a2 + a3);
    } else {
        // ---- C1 = pe @ w1 + b1 via split-bf16 MFMA, 64x64 tile, K=1024 ----
        int cid = bid - 256;  // 0..63
        int d0 = (cid & 7) * 64, s0 = (cid >> 3) * 64;
        short* sAh = smemS;
        short* sAl = smemS + 64 * CP;
        short* sBh = smemS + 2 * 64 * CP;
        short* sBl = smemS + 3 * 64 * CP;
        int w = t >> 6, l = t & 63, lc = l & 15, lg = l >> 4;
        int tm = t >> 2, tk = (t & 3) * 8;
        int bhs = (tm >> 2) & 1;  // slot of row d0+tm (d0 multiple of 64)
        f32x4 acc[4] = {};
        for (int k0 = 0; k0 < 1024; k0 += 32) {
            __syncthreads();
            *(bf16x8*)(sAh + tm * CP + tk) =
                *(const bf16x8*)(peh + (size_t)(s0 + tm) * 1024 + k0 + tk);
            *(bf16x8*)(sAl + tm * CP + tk) =
                *(const bf16x8*)(pel + (size_t)(s0 + tm) * 1024 + k0 + tk);
            size_t boff = w1t_base(d0 + tm, k0 + tk);
            *(bf16x8*)(sBh + tm * CP + tk) = *(const bf16x8*)(w1tsw + boff + bhs * 8);
            *(bf16x8*)(sBl + tm * CP + tk) = *(const bf16x8*)(w1tsw + boff + (bhs ^ 1) * 8);
            __syncthreads();
            int m = w * 16 + lc;
            bf16x8 ah = *(const bf16x8*)(sAh + m * CP + lg * 8);
            bf16x8 al = *(const bf16x8*)(sAl + m * CP + lg * 8);
#pragma unroll
            for (int j = 0; j < 4; ++j) {
                int n = j * 16 + lc;
                bf16x8 bh = *(const bf16x8*)(sBh + n * CP + lg * 8);
                bf16x8 bl = *(const bf16x8*)(sBl + n * CP + lg * 8);
                acc[j] = __builtin_amdgcn_mfma_f32_16x16x32_bf16(ah, bh, acc[j], 0, 0, 0);
                acc[j] = __builtin_amdgcn_mfma_f32_16x16x32_bf16(ah, bl, acc[j], 0, 0, 0);
                acc[j] = __builtin_amdgcn_mfma_f32_16x16x32_bf16(al, bh, acc[j], 0, 0, 0);
            }
        }
#pragma unroll
        for (int j = 0; j < 4; ++j)
#pragma unroll
            for (int reg = 0; reg < 4; ++reg) {
                int sg = s0 + w * 16 + lg * 4 + reg;
                int dg = d0 + j * 16 + lc;
                C1[(size_t)sg * D + dg] = acc[j][reg] + b1[dg];
            }
    }
}

// ---------------- main GEMM: 256x256 tile, 8 waves, BK=32, dbuf LDS ----------------
__device__ __forceinline__ void gload16(const void* src, void* dst) {
    __builtin_amdgcn_global_load_lds((const __attribute__((address_space(1))) void*)src,
                                     (__attribute__((address_space(3))) void*)dst, 16, 0, 0);
}

// split 16 consecutive fp32 of row am (half `ahalf`) into chunk-major LDS,
// slot-swizzled: hi at +((am>>2)&1)*8
__device__ __forceinline__ void split_write(short* sAbuf, int am, int ahalf,
                                            float4 a0, float4 a1, float4 a2, float4 a3) {
    int hs = (am >> 2) & 1;
#pragma unroll
    for (int cc = 0; cc < 2; ++cc) {
        float e0, e1, e2, e3, e4, e5, e6, e7;
        if (cc == 0) {
            e0 = a0.x; e1 = a0.y; e2 = a0.z; e3 = a0.w;
            e4 = a1.x; e5 = a1.y; e6 = a1.z; e7 = a1.w;
        } else {
            e0 = a2.x; e1 = a2.y; e2 = a2.z; e3 = a2.w;
            e4 = a3.x; e5 = a3.y; e6 = a3.z; e7 = a3.w;
        }
        unsigned p0 = splitf(e0), p1 = splitf(e1), p2 = splitf(e2), p3 = splitf(e3);
        unsigned p4 = splitf(e4), p5 = splitf(e5), p6 = splitf(e6), p7 = splitf(e7);
        u16x8 hi, lo;
        hi[0] = (ushort)(p0 & 0xFFFFu); lo[0] = (ushort)(p0 >> 16);
        hi[1] = (ushort)(p1 & 0xFFFFu); lo[1] = (ushort)(p1 >> 16);
        hi[2] = (ushort)(p2 & 0xFFFFu); lo[2] = (ushort)(p2 >> 16);
        hi[3] = (ushort)(p3 & 0xFFFFu); lo[3] = (ushort)(p3 >> 16);
        hi[4] = (ushort)(p4 & 0xFFFFu); lo[4] = (ushort)(p4 >> 16);
        hi[5] = (ushort)(p5 & 0xFFFFu); lo[5] = (ushort)(p5 >> 16);
        hi[6] = (ushort)(p6 & 0xFFFFu); lo[6] = (ushort)(p6 >> 16);
        hi[7] = (ushort)(p7 & 0xFFFFu); lo[7] = (ushort)(p7 >> 16);
        short* dst = sAbuf + (size_t)(2 * ahalf + cc) * 4096 + (size_t)am * 16;
        *(u16x8*)(dst + hs * 8) = hi;
        *(u16x8*)(dst + (hs ^ 1) * 8) = lo;
    }
}

__global__ __launch_bounds__(512, 2) void gemm_mfma(
    const float* __restrict__ feat, const ushort* __restrict__ w1tsw,
    const float* __restrict__ w2, const float* __restrict__ gterm,
    const float* __restrict__ C1, float* __restrict__ score, int row_base) {
    __shared__ short sA[2][4][256][16];  // [buf][kchunk][row m][2 slots x 8] — 64 KB
    __shared__ short sB[2][4][256][16];  // [buf][kchunk][row d][2 slots x 8] — 64 KB
    int t = threadIdx.x;
    // XCD-chunked bijective swizzle (256 blocks = 8 XCDs x 32): col-pairs share an XCD
    int id = (int)blockIdx.x;
    int lid = (id & 7) * 32 + (id >> 3);
    int rp = lid >> 1, cp = lid & 1;
    int row0 = row_base + (rp << 8);  // 256 rows of B*S
    int d0 = cp << 8;                 // 256 cols of D
    int b = row0 >> 9;

    // A staging mapping: 2 threads per row (halves of the 32-K tile)
    int am = t & 255, ahalf = t >> 8;
    const float4* asrc = (const float4*)(feat + (size_t)(row0 + am) * D + ahalf * 16);
    const ushort* btile = w1tsw + (size_t)(cp * 32) * 16384;
    int wv = t >> 6, l = t & 63, lc = l & 15, lg = l >> 4;
    int wr = wv >> 1, wc = wv & 1;  // wave tile: 64 rows x 128 cols
    int wbase = (t & ~63);
    int hs = (lc >> 2) & 1;          // lane-uniform slot for all fragment rows
    int oh = hs * 8, ol = (hs ^ 1) * 8;

    f32x4 acc[4][8] = {};

    // ---- prologue: stage tile 0 into buf 0 ----
    {
        float4 a0 = asrc[0], a1 = asrc[1], a2 = asrc[2], a3 = asrc[3];
#pragma unroll
        for (int q = 0; q < 4; ++q)
            gload16(btile + (size_t)(q * 512 + t) * 8,
                    &sB[0][0][0][0] + (size_t)(q * 512 + wbase) * 8);
        split_write(&sA[0][0][0][0], am, ahalf, a0, a1, a2, a3);
    }
    __syncthreads();

    for (int ts = 0; ts < 16; ++ts) {
        int cur = ts & 1, nxt = cur ^ 1;
        float4 a0, a1, a2, a3;
        if (ts < 15) {
            // issue next-tile loads early: A -> regs, B -> LDS (DMA)
            a0 = asrc[(ts + 1) * 8 + 0];
            a1 = asrc[(ts + 1) * 8 + 1];
            a2 = asrc[(ts + 1) * 8 + 2];
            a3 = asrc[(ts + 1) * 8 + 3];
#pragma unroll
            for (int q = 0; q < 4; ++q)
                gload16(btile + (size_t)(ts + 1) * 16384 + (size_t)(q * 512 + t) * 8,
                        &sB[nxt][0][0][0] + (size_t)(q * 512 + wbase) * 8);
        }
        // ---- compute on buf cur ----
        bf16x8 ahf[4], alf[4];
#pragma unroll
        for (int i = 0; i < 4; ++i) {
            const short* ap = &sA[cur][lg][wr * 64 + i * 16 + lc][0];
            ahf[i] = *(const bf16x8*)(ap + oh);
            alf[i] = *(const bf16x8*)(ap + ol);
        }
        __builtin_amdgcn_s_setprio(1);
#pragma unroll
        for (int j = 0; j < 8; ++j) {
            const short* bp = &sB[cur][lg][wc * 128 + j * 16 + lc][0];
            bf16x8 bh = *(const bf16x8*)(bp + oh);
            bf16x8 bl = *(const bf16x8*)(bp + ol);
#pragma unroll
            for (int i = 0; i < 4; ++i) {
                acc[i][j] = __builtin_amdgcn_mfma_f32_16x16x32_bf16(ahf[i], bh, acc[i][j], 0, 0, 0);
                acc[i][j] = __builtin_amdgcn_mfma_f32_16x16x32_bf16(ahf[i], bl, acc[i][j], 0, 0, 0);
                acc[i][j] = __builtin_amdgcn_mfma_f32_16x16x32_bf16(alf[i], bh, acc[i][j], 0, 0, 0);
            }
        }
        __builtin_amdgcn_s_setprio(0);
        // write-late: split A(ts+1) into the other buffer after compute
        if (ts < 15) split_write(&sA[nxt][0][0][0], am, ahalf, a0, a1, a2, a3);
        __syncthreads();  // drains vmcnt (B DMA) + lgkm (A ds_write)
    }

    // ---- epilogue: + gterm + C1, ReLU, dot w2, reduce over d, atomic score ----
    float w2v[8], gt[8];
#pragma unroll
    for (int j = 0; j < 8; ++j) {
        int d = d0 + wc * 128 + j * 16 + lc;
        w2v[j] = w2[d];
        gt[j] = gterm[b * D + d];
    }
#pragma unroll
    for (int i = 0; i < 4; ++i)
#pragma unroll
        for (int reg = 0; reg < 4; ++reg) {
            int srow = row0 + wr * 64 + i * 16 + lg * 4 + reg;
            int s = srow & 511;
            float part = 0.f;
#pragma unroll
            for (int j = 0; j < 8; ++j) {
                int d = d0 + wc * 128 + j * 16 + lc;
                float z = acc[i][j][reg] + gt[j] + C1[(size_t)s * D + d];
                part += w2v[j] * fmaxf(z, 0.f);
            }
#pragma unroll
            for (int off = 8; off; off >>= 1) part += __shfl_down(part, off, 16);
            if (lc == 0) atomicAdd(&score[srow], part);
        }
}

// ---------------- per-batch top-10 + one-hot + gather ----------------
__global__ void topk_kernel(const float* __restrict__ score, const float* __restrict__ feat,
                            float* __restrict__ out_ind, float* __restrict__ out_sel) {
    __shared__ float work[512];
    __shared__ float wvv[8];
    __shared__ int wii[8];
    __shared__ int topi[TOPK];
    int b = blockIdx.x, t = threadIdx.x;
    work[t] = score[b * S + t];
    __syncthreads();
    for (int it = 0; it < TOPK; ++it) {
        float v = work[t];
        int i = t;
#pragma unroll
        for (int off = 32; off; off >>= 1) {
            float ov = __shfl_down(v, off);
            int oi = __shfl_down(i, off);
            if (ov > v || (ov == v && oi < i)) { v = ov; i = oi; }
        }
        if ((t & 63) == 0) { wvv[t >> 6] = v; wii[t >> 6] = i; }
        __syncthreads();
        if (t == 0) {
            float bv = wvv[0];
            int bi = wii[0];
            for (int w = 1; w < 8; ++w)
                if (wvv[w] > bv || (wvv[w] == bv && wii[w] < bi)) { bv = wvv[w]; bi = wii[w]; }
            topi[it] = bi;
            work[bi] = -INFINITY;
        }
        __syncthreads();
    }
    if (t == 0) {
        for (int a = 1; a < TOPK; ++a) {
            int key = topi[a];
            int c = a - 1;
            while (c >= 0 && topi[c] > key) { topi[c + 1] = topi[c]; --c; }
            topi[c + 1] = key;
        }
    }
    __syncthreads();
    // branchless one-hot + vectorized gather (threads 0..127, float4 lanes)
    if (t < 128) {
        float4* oi4 = (float4*)(out_ind + (size_t)b * TOPK * S);
        float4* os4 = (float4*)(out_sel + (size_t)b * TOPK * D);
        const float4* fb4 = (const float4*)(feat + (size_t)b * S * D);
#pragma unroll
        for (int k = 0; k < TOPK; ++k) {
            int idx = topi[k];
            float4 ohv;
            ohv.x = (4 * t + 0 == idx) ? 1.0f : 0.0f;
            ohv.y = (4 * t + 1 == idx) ? 1.0f : 0.0f;
            ohv.z = (4 * t + 2 == idx) ? 1.0f : 0.0f;
            ohv.w = (4 * t + 3 == idx) ? 1.0f : 0.0f;
            oi4[k * (S / 4) + t] = ohv;
            os4[k * (D / 4) + t] = fb4[(size_t)idx * (D / 4) + t];
        }
    }
}

extern "C" void kernel_launch(void* const* d_in, const int* in_sizes, int n_in,
                              void* d_out, int out_size, void* d_ws, size_t ws_size,
                              hipStream_t stream) {
    const float* x  = (const float*)d_in[0];
    const float* w1 = (const float*)d_in[1];
    const float* b1 = (const float*)d_in[2];
    const float* w2 = (const float*)d_in[3];
    // b2 (d_in[4]): uniform score shift, ranking-invariant -> dropped.

    float* out = (float*)d_out;
    float* out_ind = out;                              // [B,10,S]
    float* out_sel = out + (size_t)B * TOPK * S;       // [B,10,D]
    float* feat    = out + 2 * (size_t)B * TOPK * S;   // [B,S,D]

    float* ws      = (float*)d_ws;
    float* g       = ws;                       // [B*D]
    float* score   = ws + 65536;               // [B*S]
    float* gterm   = ws + 131072;              // [B*D]
    float* C1      = ws + 196608;              // [S*D]
    ushort* w1tsw  = (ushort*)(ws + 458752);   // [2][32][4][256][16] ushorts, slot-swizzled
    ushort* peh    = (ushort*)(ws + 983040);   // [512][1024] bf16 (row-major)
    ushort* pel    = (ushort*)(ws + 1245184);

    zero_kernel<<<512, 256, 0, stream>>>(ws);  // g + score
    fused_stage1<<<8768, 256, 0, stream>>>(x, feat, g, peh, pel, w1, w1tsw);
    fused_stage2<<<320, 256, 0, stream>>>(g, w1, gterm, peh, pel, w1tsw, b1, C1);
    gemm_mfma<<<256, 512, 0, stream>>>(feat, w1tsw, w2, gterm, C1, score, 0);
    gemm_mfma<<<256, 512, 0, stream>>>(feat, w1tsw, w2, gterm, C1, score, 32768);
    topk_kernel<<<B, 512, 0, stream>>>(score, feat, out_ind, out_sel);
}

// Round 6
// 406.275 us; speedup vs baseline: 1.0295x; 1.0295x over previous
//
#include <hip/hip_runtime.h>
#include <math.h>

#define B 128
#define D 512
#define S 512
#define TOPK 10

typedef short bf16x8 __attribute__((ext_vector_type(8)));
typedef unsigned short u16x8 __attribute__((ext_vector_type(8)));
typedef float f32x4 __attribute__((ext_vector_type(4)));

// -------- workspace layout (floats) --------
// score  @ 0        [65536]     (zeroed inside fused_stage2 gterm blocks)
// gterm  @ 65536    [65536]     (written directly)
// g_part @ 131072   [524288]    ([8 sblk][128 b][512 d], written directly - no zero)
// C1     @ 655360   [262144]
// w1tsw  @ 917504   [524288]    (ushort [2 rp][32 ts][4 kc][256 m][16], slot-swizzled)
// peh    @ 1441792  [262144]    (512 s x 1024 f bf16, row-major)
// pel    @ 1703936  [262144]
// total 1966080 floats = 7.5 MB
//
// slot swizzle: row m's hi 8 ushorts live at +((m>>2)&1)*8, lo at the other slot.
// quad(m,h) = (2*(m&3) + (h ^ ((m>>2)&1))) & 7 sweeps all 8 LDS bank-quads over any
// 8 consecutive rows -> b128 fragment reads/writes hit the 8-cycle floor.

// ---------------- split fp32 -> (hi bf16 RNE, lo bf16 RZ), packed ----------------
__device__ __forceinline__ unsigned splitf(float f) {
    unsigned u = __float_as_uint(f);
    unsigned rb = u + 0x7FFFu + ((u >> 16) & 1u);  // RNE to bf16
    float hf = __uint_as_float(rb & 0xFFFF0000u);
    unsigned u2 = __float_as_uint(f - hf);  // exact residual
    return (rb >> 16) | (u2 & 0xFFFF0000u);
}

// element-offset (ushorts) of row-base of (d,k) in w1tsw; hi slot = +((d>>2)&1)*8
__device__ __forceinline__ size_t w1t_base(int d, int k) {
    return (size_t)(((d >> 8) * 32 + (k >> 5)) * 4 + ((k >> 3) & 3)) * 4096 +
           (size_t)(d & 255) * 16 + (k & 7);
}

// ---------------- fused stage 1: transpose+mean | pe | w1split ----------------
// 512 threads/block. blocks [0,4096): transpose 128d x 64s tile;
// [4096,4608): pe row; [4608,4672): w1split (rp,tt)
__global__ __launch_bounds__(512) void fused_stage1(
    const float* __restrict__ x, float* __restrict__ feat, float* __restrict__ g_part,
    ushort* __restrict__ peh, ushort* __restrict__ pel,
    const float* __restrict__ w1, ushort* __restrict__ w1tsw) {
    __shared__ float tile[64 * 129];  // addr(d,s) = d + s*129  (129 odd -> ~2-way max)
    int bid = (int)blockIdx.x;
    int t = threadIdx.x;

    if (bid < 4096) {
        // ---- transpose + mean: feat[b,s,d] = x[b,d,s]; g_part direct write ----
        int b = bid >> 5;
        int d0 = ((bid >> 3) & 3) * 128;
        int sblk = bid & 7;
        int s0 = sblk * 64;
        int ty = t >> 4, tx = t & 15;  // ty 0..31 (d rows), tx 0..15 (s chunks)
        const float4* x4 = (const float4*)(x + (size_t)b * D * S);
        float psum[4];
#pragma unroll
        for (int q = 0; q < 4; ++q) {
            int d = ty + 32 * q;
            float4 v = x4[(size_t)(d0 + d) * (S / 4) + (s0 >> 2) + tx];
            tile[d + (4 * tx + 0) * 129] = v.x;
            tile[d + (4 * tx + 1) * 129] = v.y;
            tile[d + (4 * tx + 2) * 129] = v.z;
            tile[d + (4 * tx + 3) * 129] = v.w;
            float sm = (v.x + v.y) + (v.z + v.w);
#pragma unroll
            for (int off = 8; off; off >>= 1) sm += __shfl_down(sm, off, 16);
            psum[q] = sm;
        }
        if (tx == 0) {
            float* gp = g_part + (size_t)sblk * 65536 + b * D + d0;
#pragma unroll
            for (int q = 0; q < 4; ++q) gp[ty + 32 * q] = psum[q] * (1.0f / S);
        }
        __syncthreads();
        // write-out: 64 s rows x 128 d; fx = d-chunk (32 per row), nt stores
        int fx = t & 31, sy = t >> 5;  // fx 0..31, sy 0..15
        float* fbase = feat + (size_t)b * S * D + d0 + 4 * fx;
#pragma unroll
        for (int j = 0; j < 4; ++j) {
            int s = sy + 16 * j;
            f32x4 o;
            o[0] = tile[(4 * fx + 0) + s * 129];
            o[1] = tile[(4 * fx + 1) + s * 129];
            o[2] = tile[(4 * fx + 2) + s * 129];
            o[3] = tile[(4 * fx + 3) + s * 129];
            __builtin_nontemporal_store(o, (f32x4*)(fbase + (size_t)(s0 + s) * D));
        }
    } else if (bid < 4608) {
        // ---- pe precompute + split: pe[s][f], f=2i sin / 2i+1 cos ----
        int s = bid - 4096;
        int i = t;  // 0..511
        float ei = expf((float)(2 * i) * -0.0089944730195f);  // -ln(10000)/1024 * 2i
        float ang = (float)s * ei;
        float sv = sinf(ang), cv = cosf(ang);
        unsigned ps = splitf(sv), pc = splitf(cv);
        size_t base = (size_t)s * 1024 + 2 * i;
        peh[base] = (ushort)(ps & 0xFFFFu);
        peh[base + 1] = (ushort)(pc & 0xFFFFu);
        pel[base] = (ushort)(ps >> 16);
        pel[base + 1] = (ushort)(pc >> 16);
    } else {
        // ---- w1 split+transpose into tiled chunk-major slot-swizzled layout ----
        int id2 = bid - 4608;  // 0..63
        int rp = id2 & 1, tt = id2 >> 1;
        int m = t & 255;
        int c0 = (t >> 8) * 2;
        int d = rp * 256 + m;
        int hs = (m >> 2) & 1;
        ushort* outp = w1tsw + (size_t)(rp * 32 + tt) * 16384 + (size_t)m * 16;
#pragma unroll
        for (int cc = 0; cc < 2; ++cc) {
            int c = c0 + cc;
            u16x8 hi, lo;
#pragma unroll
            for (int j = 0; j < 8; ++j) {
                unsigned p = splitf(w1[(size_t)(tt * 32 + c * 8 + j) * D + d]);
                hi[j] = (ushort)(p & 0xFFFFu);
                lo[j] = (ushort)(p >> 16);
            }
            *(u16x8*)(outp + c * 4096 + hs * 8) = hi;
            *(u16x8*)(outp + c * 4096 + (hs ^ 1) * 8) = lo;
        }
    }
}

// ---------------- fused stage 2: score-zero + gterm | c1 ----------------
#define CP 40
// blocks [0,256): zero score slice + gterm for (b, half); [256,320): c1 64x64 tile
__global__ __launch_bounds__(256) void fused_stage2(
    const float* __restrict__ g_part, const float* __restrict__ w1,
    float* __restrict__ gterm, float* __restrict__ score,
    const ushort* __restrict__ peh, const ushort* __restrict__ pel,
    const ushort* __restrict__ w1tsw, const float* __restrict__ b1,
    float* __restrict__ C1) {
    __shared__ short smemS[4 * 64 * CP];  // c1: 4 arrays; gterm: 512 floats at front
    int bid = (int)blockIdx.x;
    int t = threadIdx.x;

    if (bid < 256) {
        // ---- zero a 256-float slice of score ----
        score[bid * 256 + t] = 0.0f;
        // ---- gterm[b,d] = sum_k g[b,k] * w1[D+k, d]; g = sum of 8 partials ----
        int b = bid >> 1, half = bid & 1;
        float* gs = (float*)smemS;
#pragma unroll
        for (int h = 0; h < 2; ++h) {
            int k = h * 256 + t;
            float acc = 0.f;
#pragma unroll
            for (int sb = 0; sb < 8; ++sb) acc += g_part[(size_t)sb * 65536 + b * D + k];
            gs[k] = acc;
        }
        __syncthreads();
        int d = half * 256 + t;
        float a0 = 0.f, a1 = 0.f, a2 = 0.f, a3 = 0.f;
        for (int k = 0; k < 512; k += 4) {
            a0 += gs[k + 0] * w1[(size_t)(D + k + 0) * D + d];
            a1 += gs[k + 1] * w1[(size_t)(D + k + 1) * D + d];
            a2 += gs[k + 2] * w1[(size_t)(D + k + 2) * D + d];
            a3 += gs[k + 3] * w1[(size_t)(D + k + 3) * D + d];
        }
        gterm[b * D + d] = (a0 + a1) + (a2 + a3);
    } else {
        // ---- C1 = pe @ w1 + b1 via split-bf16 MFMA, 64x64 tile, K=1024 ----
        int cid = bid - 256;  // 0..63
        int d0 = (cid & 7) * 64, s0 = (cid >> 3) * 64;
        short* sAh = smemS;
        short* sAl = smemS + 64 * CP;
        short* sBh = smemS + 2 * 64 * CP;
        short* sBl = smemS + 3 * 64 * CP;
        int w = t >> 6, l = t & 63, lc = l & 15, lg = l >> 4;
        int tm = t >> 2, tk = (t & 3) * 8;
        int bhs = (tm >> 2) & 1;  // slot of row d0+tm (d0 multiple of 64)
        f32x4 acc[4] = {};
        for (int k0 = 0; k0 < 1024; k0 += 32) {
            __syncthreads();
            *(bf16x8*)(sAh + tm * CP + tk) =
                *(const bf16x8*)(peh + (size_t)(s0 + tm) * 1024 + k0 + tk);
            *(bf16x8*)(sAl + tm * CP + tk) =
                *(const bf16x8*)(pel + (size_t)(s0 + tm) * 1024 + k0 + tk);
            size_t boff = w1t_base(d0 + tm, k0 + tk);
            *(bf16x8*)(sBh + tm * CP + tk) = *(const bf16x8*)(w1tsw + boff + bhs * 8);
            *(bf16x8*)(sBl + tm * CP + tk) = *(const bf16x8*)(w1tsw + boff + (bhs ^ 1) * 8);
            __syncthreads();
            int m = w * 16 + lc;
            bf16x8 ah = *(const bf16x8*)(sAh + m * CP + lg * 8);
            bf16x8 al = *(const bf16x8*)(sAl + m * CP + lg * 8);
#pragma unroll
            for (int j = 0; j < 4; ++j) {
                int n = j * 16 + lc;
                bf16x8 bh = *(const bf16x8*)(sBh + n * CP + lg * 8);
                bf16x8 bl = *(const bf16x8*)(sBl + n * CP + lg * 8);
                acc[j] = __builtin_amdgcn_mfma_f32_16x16x32_bf16(ah, bh, acc[j], 0, 0, 0);
                acc[j] = __builtin_amdgcn_mfma_f32_16x16x32_bf16(ah, bl, acc[j], 0, 0, 0);
                acc[j] = __builtin_amdgcn_mfma_f32_16x16x32_bf16(al, bh, acc[j], 0, 0, 0);
            }
        }
#pragma unroll
        for (int j = 0; j < 4; ++j)
#pragma unroll
            for (int reg = 0; reg < 4; ++reg) {
                int sg = s0 + w * 16 + lg * 4 + reg;
                int dg = d0 + j * 16 + lc;
                C1[(size_t)sg * D + dg] = acc[j][reg] + b1[dg];
            }
    }
}

// ---------------- main GEMM: 256x256 tile, 8 waves, BK=32, dbuf LDS ----------------
__device__ __forceinline__ void gload16(const void* src, void* dst) {
    __builtin_amdgcn_global_load_lds((const __attribute__((address_space(1))) void*)src,
                                     (__attribute__((address_space(3))) void*)dst, 16, 0, 0);
}

// split 16 consecutive fp32 of row am (half `ahalf`) into chunk-major LDS,
// slot-swizzled: hi at +((am>>2)&1)*8
__device__ __forceinline__ void split_write(short* sAbuf, int am, int ahalf,
                                            float4 a0, float4 a1, float4 a2, float4 a3) {
    int hs = (am >> 2) & 1;
#pragma unroll
    for (int cc = 0; cc < 2; ++cc) {
        float e0, e1, e2, e3, e4, e5, e6, e7;
        if (cc == 0) {
            e0 = a0.x; e1 = a0.y; e2 = a0.z; e3 = a0.w;
            e4 = a1.x; e5 = a1.y; e6 = a1.z; e7 = a1.w;
        } else {
            e0 = a2.x; e1 = a2.y; e2 = a2.z; e3 = a2.w;
            e4 = a3.x; e5 = a3.y; e6 = a3.z; e7 = a3.w;
        }
        unsigned p0 = splitf(e0), p1 = splitf(e1), p2 = splitf(e2), p3 = splitf(e3);
        unsigned p4 = splitf(e4), p5 = splitf(e5), p6 = splitf(e6), p7 = splitf(e7);
        u16x8 hi, lo;
        hi[0] = (ushort)(p0 & 0xFFFFu); lo[0] = (ushort)(p0 >> 16);
        hi[1] = (ushort)(p1 & 0xFFFFu); lo[1] = (ushort)(p1 >> 16);
        hi[2] = (ushort)(p2 & 0xFFFFu); lo[2] = (ushort)(p2 >> 16);
        hi[3] = (ushort)(p3 & 0xFFFFu); lo[3] = (ushort)(p3 >> 16);
        hi[4] = (ushort)(p4 & 0xFFFFu); lo[4] = (ushort)(p4 >> 16);
        hi[5] = (ushort)(p5 & 0xFFFFu); lo[5] = (ushort)(p5 >> 16);
        hi[6] = (ushort)(p6 & 0xFFFFu); lo[6] = (ushort)(p6 >> 16);
        hi[7] = (ushort)(p7 & 0xFFFFu); lo[7] = (ushort)(p7 >> 16);
        short* dst = sAbuf + (size_t)(2 * ahalf + cc) * 4096 + (size_t)am * 16;
        *(u16x8*)(dst + hs * 8) = hi;
        *(u16x8*)(dst + (hs ^ 1) * 8) = lo;
    }
}

__global__ __launch_bounds__(512, 2) void gemm_mfma(
    const float* __restrict__ feat, const ushort* __restrict__ w1tsw,
    const float* __restrict__ w2, const float* __restrict__ gterm,
    const float* __restrict__ C1, float* __restrict__ score, int row_base) {
    __shared__ short sA[2][4][256][16];  // [buf][kchunk][row m][2 slots x 8] — 64 KB
    __shared__ short sB[2][4][256][16];  // [buf][kchunk][row d][2 slots x 8] — 64 KB
    int t = threadIdx.x;
    // XCD-chunked bijective swizzle (256 blocks = 8 XCDs x 32): col-pairs share an XCD
    int id = (int)blockIdx.x;
    int lid = (id & 7) * 32 + (id >> 3);
    int rp = lid >> 1, cp = lid & 1;
    int row0 = row_base + (rp << 8);  // 256 rows of B*S
    int d0 = cp << 8;                 // 256 cols of D
    int b = row0 >> 9;

    // A staging mapping: 2 threads per row (halves of the 32-K tile)
    int am = t & 255, ahalf = t >> 8;
    const float4* asrc = (const float4*)(feat + (size_t)(row0 + am) * D + ahalf * 16);
    const ushort* btile = w1tsw + (size_t)(cp * 32) * 16384;
    int wv = t >> 6, l = t & 63, lc = l & 15, lg = l >> 4;
    int wr = wv >> 1, wc = wv & 1;  // wave tile: 64 rows x 128 cols
    int wbase = (t & ~63);
    int hs = (lc >> 2) & 1;          // lane-uniform slot for all fragment rows
    int oh = hs * 8, ol = (hs ^ 1) * 8;

    f32x4 acc[4][8] = {};

    // ---- prologue: stage tile 0 into buf 0 ----
    {
        float4 a0 = asrc[0], a1 = asrc[1], a2 = asrc[2], a3 = asrc[3];
#pragma unroll
        for (int q = 0; q < 4; ++q)
            gload16(btile + (size_t)(q * 512 + t) * 8,
                    &sB[0][0][0][0] + (size_t)(q * 512 + wbase) * 8);
        split_write(&sA[0][0][0][0], am, ahalf, a0, a1, a2, a3);
    }
    __syncthreads();

    for (int ts = 0; ts < 16; ++ts) {
        int cur = ts & 1, nxt = cur ^ 1;
        float4 a0, a1, a2, a3;
        if (ts < 15) {
            // issue next-tile loads early: A -> regs, B -> LDS (DMA)
            a0 = asrc[(ts + 1) * 8 + 0];
            a1 = asrc[(ts + 1) * 8 + 1];
            a2 = asrc[(ts + 1) * 8 + 2];
            a3 = asrc[(ts + 1) * 8 + 3];
#pragma unroll
            for (int q = 0; q < 4; ++q)
                gload16(btile + (size_t)(ts + 1) * 16384 + (size_t)(q * 512 + t) * 8,
                        &sB[nxt][0][0][0] + (size_t)(q * 512 + wbase) * 8);
        }
        // ---- compute on buf cur ----
        bf16x8 ahf[4], alf[4];
#pragma unroll
        for (int i = 0; i < 4; ++i) {
            const short* ap = &sA[cur][lg][wr * 64 + i * 16 + lc][0];
            ahf[i] = *(const bf16x8*)(ap + oh);
            alf[i] = *(const bf16x8*)(ap + ol);
        }
        __builtin_amdgcn_s_setprio(1);
#pragma unroll
        for (int j = 0; j < 8; ++j) {
            const short* bp = &sB[cur][lg][wc * 128 + j * 16 + lc][0];
            bf16x8 bh = *(const bf16x8*)(bp + oh);
            bf16x8 bl = *(const bf16x8*)(bp + ol);
#pragma unroll
            for (int i = 0; i < 4; ++i) {
                acc[i][j] = __builtin_amdgcn_mfma_f32_16x16x32_bf16(ahf[i], bh, acc[i][j], 0, 0, 0);
                acc[i][j] = __builtin_amdgcn_mfma_f32_16x16x32_bf16(ahf[i], bl, acc[i][j], 0, 0, 0);
                acc[i][j] = __builtin_amdgcn_mfma_f32_16x16x32_bf16(alf[i], bh, acc[i][j], 0, 0, 0);
            }
        }
        __builtin_amdgcn_s_setprio(0);
        // write-late: split A(ts+1) into the other buffer after compute
        if (ts < 15) split_write(&sA[nxt][0][0][0], am, ahalf, a0, a1, a2, a3);
        __syncthreads();  // drains vmcnt (B DMA) + lgkm (A ds_write)
    }

    // ---- epilogue: + gterm + C1, ReLU, dot w2, reduce over d, atomic score ----
    float w2v[8], gt[8];
#pragma unroll
    for (int j = 0; j < 8; ++j) {
        int d = d0 + wc * 128 + j * 16 + lc;
        w2v[j] = w2[d];
        gt[j] = gterm[b * D + d];
    }
#pragma unroll
    for (int i = 0; i < 4; ++i)
#pragma unroll
        for (int reg = 0; reg < 4; ++reg) {
            int srow = row0 + wr * 64 + i * 16 + lg * 4 + reg;
            int s = srow & 511;
            float part = 0.f;
#pragma unroll
            for (int j = 0; j < 8; ++j) {
                int d = d0 + wc * 128 + j * 16 + lc;
                float z = acc[i][j][reg] + gt[j] + C1[(size_t)s * D + d];
                part += w2v[j] * fmaxf(z, 0.f);
            }
#pragma unroll
            for (int off = 8; off; off >>= 1) part += __shfl_down(part, off, 16);
            if (lc == 0) atomicAdd(&score[srow], part);
        }
}

// ---------------- per-batch top-10 + one-hot + gather ----------------
__global__ void topk_kernel(const float* __restrict__ score, const float* __restrict__ feat,
                            float* __restrict__ out_ind, float* __restrict__ out_sel) {
    __shared__ float work[512];
    __shared__ float wvv[8];
    __shared__ int wii[8];
    __shared__ int topi[TOPK];
    int b = blockIdx.x, t = threadIdx.x;
    work[t] = score[b * S + t];
    __syncthreads();
    for (int it = 0; it < TOPK; ++it) {
        float v = work[t];
        int i = t;
#pragma unroll
        for (int off = 32; off; off >>= 1) {
            float ov = __shfl_down(v, off);
            int oi = __shfl_down(i, off);
            if (ov > v || (ov == v && oi < i)) { v = ov; i = oi; }
        }
        if ((t & 63) == 0) { wvv[t >> 6] = v; wii[t >> 6] = i; }
        __syncthreads();
        if (t == 0) {
            float bv = wvv[0];
            int bi = wii[0];
            for (int w = 1; w < 8; ++w)
                if (wvv[w] > bv || (wvv[w] == bv && wii[w] < bi)) { bv = wvv[w]; bi = wii[w]; }
            topi[it] = bi;
            work[bi] = -INFINITY;
        }
        __syncthreads();
    }
    if (t == 0) {
        for (int a = 1; a < TOPK; ++a) {
            int key = topi[a];
            int c = a - 1;
            while (c >= 0 && topi[c] > key) { topi[c + 1] = topi[c]; --c; }
            topi[c + 1] = key;
        }
    }
    __syncthreads();
    // branchless one-hot + vectorized gather (threads 0..127, float4 lanes)
    if (t < 128) {
        float4* oi4 = (float4*)(out_ind + (size_t)b * TOPK * S);
        float4* os4 = (float4*)(out_sel + (size_t)b * TOPK * D);
        const float4* fb4 = (const float4*)(feat + (size_t)b * S * D);
#pragma unroll
        for (int k = 0; k < TOPK; ++k) {
            int idx = topi[k];
            float4 ohv;
            ohv.x = (4 * t + 0 == idx) ? 1.0f : 0.0f;
            ohv.y = (4 * t + 1 == idx) ? 1.0f : 0.0f;
            ohv.z = (4 * t + 2 == idx) ? 1.0f : 0.0f;
            ohv.w = (4 * t + 3 == idx) ? 1.0f : 0.0f;
            oi4[k * (S / 4) + t] = ohv;
            os4[k * (D / 4) + t] = fb4[(size_t)idx * (D / 4) + t];
        }
    }
}

extern "C" void kernel_launch(void* const* d_in, const int* in_sizes, int n_in,
                              void* d_out, int out_size, void* d_ws, size_t ws_size,
                              hipStream_t stream) {
    const float* x  = (const float*)d_in[0];
    const float* w1 = (const float*)d_in[1];
    const float* b1 = (const float*)d_in[2];
    const float* w2 = (const float*)d_in[3];
    // b2 (d_in[4]): uniform score shift, ranking-invariant -> dropped.

    float* out = (float*)d_out;
    float* out_ind = out;                              // [B,10,S]
    float* out_sel = out + (size_t)B * TOPK * S;       // [B,10,D]
    float* feat    = out + 2 * (size_t)B * TOPK * S;   // [B,S,D]

    float* ws      = (float*)d_ws;
    float* score   = ws;                        // [B*S]
    float* gterm   = ws + 65536;                // [B*D]
    float* g_part  = ws + 131072;               // [8][B][D]
    float* C1      = ws + 655360;               // [S*D]
    ushort* w1tsw  = (ushort*)(ws + 917504);    // [2][32][4][256][16] ushorts, slot-swizzled
    ushort* peh    = (ushort*)(ws + 1441792);   // [512][1024] bf16 (row-major)
    ushort* pel    = (ushort*)(ws + 1703936);

    fused_stage1<<<4672, 512, 0, stream>>>(x, feat, g_part, peh, pel, w1, w1tsw);
    fused_stage2<<<320, 256, 0, stream>>>(g_part, w1, gterm, score, peh, pel, w1tsw, b1, C1);
    gemm_mfma<<<256, 512, 0, stream>>>(feat, w1tsw, w2, gterm, C1, score, 0);
    gemm_mfma<<<256, 512, 0, stream>>>(feat, w1tsw, w2, gterm, C1, score, 32768);
    topk_kernel<<<B, 512, 0, stream>>>(score, feat, out_ind, out_sel);
}

// Round 7
// 387.562 us; speedup vs baseline: 1.0792x; 1.0483x over previous
//
#include <hip/hip_runtime.h>
#include <math.h>

#define B 128
#define D 512
#define S 512
#define TOPK 10

typedef short bf16x8 __attribute__((ext_vector_type(8)));
typedef unsigned short u16x8 __attribute__((ext_vector_type(8)));
typedef float f32x4 __attribute__((ext_vector_type(4)));

// -------- workspace layout (floats) --------
// score  @ 0        [65536]     (zeroed inside fused_stage2 gterm blocks)
// gterm  @ 65536    [65536]     (written directly)
// g_part @ 131072   [524288]    ([8 sblk][128 b][512 d], written directly - no zero)
// C1     @ 655360   [262144]
// w1tsw  @ 917504   [524288]    (ushort [2 rp][32 ts][4 kc][256 m][16], slot-swizzled)
// peh    @ 1441792  [262144]    (512 s x 1024 f bf16, row-major)
// pel    @ 1703936  [262144]
//
// slot swizzle: row m's hi 8 ushorts live at +((m>>2)&1)*8, lo at the other slot.
// quad(m,h) = (2*(m&3) + (h ^ ((m>>2)&1))) & 7 sweeps all 8 LDS bank-quads over any
// 8 consecutive rows -> b128 fragment reads/writes hit the 8-cycle floor.

// ---------------- split fp32 -> (hi bf16 RNE, lo bf16 RZ), packed ----------------
__device__ __forceinline__ unsigned splitf(float f) {
    unsigned u = __float_as_uint(f);
    unsigned rb = u + 0x7FFFu + ((u >> 16) & 1u);  // RNE to bf16
    float hf = __uint_as_float(rb & 0xFFFF0000u);
    unsigned u2 = __float_as_uint(f - hf);  // exact residual
    return (rb >> 16) | (u2 & 0xFFFF0000u);
}

// element-offset (ushorts) of row-base of (d,k) in w1tsw; hi slot = +((d>>2)&1)*8
__device__ __forceinline__ size_t w1t_base(int d, int k) {
    return (size_t)(((d >> 8) * 32 + (k >> 5)) * 4 + ((k >> 3) & 3)) * 4096 +
           (size_t)(d & 255) * 16 + (k & 7);
}

// ---------------- fused stage 1: transpose+mean | pe | w1split ----------------
// 512 threads/block. blocks [0,4096): transpose 128d x 64s tile;
// [4096,4608): pe row; [4608,4672): w1split (rp,tt)
__global__ __launch_bounds__(512) void fused_stage1(
    const float* __restrict__ x, float* __restrict__ feat, float* __restrict__ g_part,
    ushort* __restrict__ peh, ushort* __restrict__ pel,
    const float* __restrict__ w1, ushort* __restrict__ w1tsw) {
    __shared__ float tile[64 * 129];  // addr(d,s) = d + s*129  (129 odd -> ~2-way max)
    int bid = (int)blockIdx.x;
    int t = threadIdx.x;

    if (bid < 4096) {
        // ---- transpose + mean: feat[b,s,d] = x[b,d,s]; g_part direct write ----
        int b = bid >> 5;
        int d0 = ((bid >> 3) & 3) * 128;
        int sblk = bid & 7;
        int s0 = sblk * 64;
        int ty = t >> 4, tx = t & 15;  // ty 0..31 (d rows), tx 0..15 (s chunks)
        const float4* x4 = (const float4*)(x + (size_t)b * D * S);
        float psum[4];
#pragma unroll
        for (int q = 0; q < 4; ++q) {
            int d = ty + 32 * q;
            float4 v = x4[(size_t)(d0 + d) * (S / 4) + (s0 >> 2) + tx];
            tile[d + (4 * tx + 0) * 129] = v.x;
            tile[d + (4 * tx + 1) * 129] = v.y;
            tile[d + (4 * tx + 2) * 129] = v.z;
            tile[d + (4 * tx + 3) * 129] = v.w;
            float sm = (v.x + v.y) + (v.z + v.w);
#pragma unroll
            for (int off = 8; off; off >>= 1) sm += __shfl_down(sm, off, 16);
            psum[q] = sm;
        }
        if (tx == 0) {
            float* gp = g_part + (size_t)sblk * 65536 + b * D + d0;
#pragma unroll
            for (int q = 0; q < 4; ++q) gp[ty + 32 * q] = psum[q] * (1.0f / S);
        }
        __syncthreads();
        // write-out: 64 s rows x 128 d; fx = d-chunk (32 per row), nt stores
        int fx = t & 31, sy = t >> 5;  // fx 0..31, sy 0..15
        float* fbase = feat + (size_t)b * S * D + d0 + 4 * fx;
#pragma unroll
        for (int j = 0; j < 4; ++j) {
            int s = sy + 16 * j;
            f32x4 o;
            o[0] = tile[(4 * fx + 0) + s * 129];
            o[1] = tile[(4 * fx + 1) + s * 129];
            o[2] = tile[(4 * fx + 2) + s * 129];
            o[3] = tile[(4 * fx + 3) + s * 129];
            __builtin_nontemporal_store(o, (f32x4*)(fbase + (size_t)(s0 + s) * D));
        }
    } else if (bid < 4608) {
        // ---- pe precompute + split: pe[s][f], f=2i sin / 2i+1 cos ----
        int s = bid - 4096;
        int i = t;  // 0..511
        float ei = expf((float)(2 * i) * -0.0089944730195f);  // -ln(10000)/1024 * 2i
        float ang = (float)s * ei;
        float sv, cv;
        sincosf(ang, &sv, &cv);
        unsigned ps = splitf(sv), pc = splitf(cv);
        size_t base = (size_t)s * 1024 + 2 * i;
        peh[base] = (ushort)(ps & 0xFFFFu);
        peh[base + 1] = (ushort)(pc & 0xFFFFu);
        pel[base] = (ushort)(ps >> 16);
        pel[base + 1] = (ushort)(pc >> 16);
    } else {
        // ---- w1 split+transpose into tiled chunk-major slot-swizzled layout ----
        int id2 = bid - 4608;  // 0..63
        int rp = id2 & 1, tt = id2 >> 1;
        int m = t & 255;
        int c0 = (t >> 8) * 2;
        int d = rp * 256 + m;
        int hs = (m >> 2) & 1;
        ushort* outp = w1tsw + (size_t)(rp * 32 + tt) * 16384 + (size_t)m * 16;
#pragma unroll
        for (int cc = 0; cc < 2; ++cc) {
            int c = c0 + cc;
            u16x8 hi, lo;
#pragma unroll
            for (int j = 0; j < 8; ++j) {
                unsigned p = splitf(w1[(size_t)(tt * 32 + c * 8 + j) * D + d]);
                hi[j] = (ushort)(p & 0xFFFFu);
                lo[j] = (ushort)(p >> 16);
            }
            *(u16x8*)(outp + c * 4096 + hs * 8) = hi;
            *(u16x8*)(outp + c * 4096 + (hs ^ 1) * 8) = lo;
        }
    }
}

// ---------------- fused stage 2: score-zero + gterm | c1 ----------------
#define CP 40
// blocks [0,256): zero score slice + gterm for (b, half); [256,320): c1 64x64 tile
__global__ __launch_bounds__(256) void fused_stage2(
    const float* __restrict__ g_part, const float* __restrict__ w1,
    float* __restrict__ gterm, float* __restrict__ score,
    const ushort* __restrict__ peh, const ushort* __restrict__ pel,
    const ushort* __restrict__ w1tsw, const float* __restrict__ b1,
    float* __restrict__ C1) {
    __shared__ short smemS[4 * 64 * CP];  // c1: 4 arrays; gterm: 512 floats at front
    int bid = (int)blockIdx.x;
    int t = threadIdx.x;

    if (bid < 256) {
        // ---- zero a 256-float slice of score ----
        score[bid * 256 + t] = 0.0f;
        // ---- gterm[b,d] = sum_k g[b,k] * w1[D+k, d]; g = sum of 8 partials ----
        int b = bid >> 1, half = bid & 1;
        float* gs = (float*)smemS;
#pragma unroll
        for (int h = 0; h < 2; ++h) {
            int k = h * 256 + t;
            float acc = 0.f;
#pragma unroll
            for (int sb = 0; sb < 8; ++sb) acc += g_part[(size_t)sb * 65536 + b * D + k];
            gs[k] = acc;
        }
        __syncthreads();
        int d = half * 256 + t;
        float a0 = 0.f, a1 = 0.f, a2 = 0.f, a3 = 0.f;
        for (int k = 0; k < 512; k += 4) {
            a0 += gs[k + 0] * w1[(size_t)(D + k + 0) * D + d];
            a1 += gs[k + 1] * w1[(size_t)(D + k + 1) * D + d];
            a2 += gs[k + 2] * w1[(size_t)(D + k + 2) * D + d];
            a3 += gs[k + 3] * w1[(size_t)(D + k + 3) * D + d];
        }
        gterm[b * D + d] = (a0 + a1) + (a2 + a3);
    } else {
        // ---- C1 = pe @ w1 + b1 via split-bf16 MFMA, 64x64 tile, K=1024 ----
        int cid = bid - 256;  // 0..63
        int d0 = (cid & 7) * 64, s0 = (cid >> 3) * 64;
        short* sAh = smemS;
        short* sAl = smemS + 64 * CP;
        short* sBh = smemS + 2 * 64 * CP;
        short* sBl = smemS + 3 * 64 * CP;
        int w = t >> 6, l = t & 63, lc = l & 15, lg = l >> 4;
        int tm = t >> 2, tk = (t & 3) * 8;
        int bhs = (tm >> 2) & 1;  // slot of row d0+tm (d0 multiple of 64)
        f32x4 acc[4] = {};
        for (int k0 = 0; k0 < 1024; k0 += 32) {
            __syncthreads();
            *(bf16x8*)(sAh + tm * CP + tk) =
                *(const bf16x8*)(peh + (size_t)(s0 + tm) * 1024 + k0 + tk);
            *(bf16x8*)(sAl + tm * CP + tk) =
                *(const bf16x8*)(pel + (size_t)(s0 + tm) * 1024 + k0 + tk);
            size_t boff = w1t_base(d0 + tm, k0 + tk);
            *(bf16x8*)(sBh + tm * CP + tk) = *(const bf16x8*)(w1tsw + boff + bhs * 8);
            *(bf16x8*)(sBl + tm * CP + tk) = *(const bf16x8*)(w1tsw + boff + (bhs ^ 1) * 8);
            __syncthreads();
            int m = w * 16 + lc;
            bf16x8 ah = *(const bf16x8*)(sAh + m * CP + lg * 8);
            bf16x8 al = *(const bf16x8*)(sAl + m * CP + lg * 8);
#pragma unroll
            for (int j = 0; j < 4; ++j) {
                int n = j * 16 + lc;
                bf16x8 bh = *(const bf16x8*)(sBh + n * CP + lg * 8);
                bf16x8 bl = *(const bf16x8*)(sBl + n * CP + lg * 8);
                acc[j] = __builtin_amdgcn_mfma_f32_16x16x32_bf16(ah, bh, acc[j], 0, 0, 0);
                acc[j] = __builtin_amdgcn_mfma_f32_16x16x32_bf16(ah, bl, acc[j], 0, 0, 0);
                acc[j] = __builtin_amdgcn_mfma_f32_16x16x32_bf16(al, bh, acc[j], 0, 0, 0);
            }
        }
#pragma unroll
        for (int j = 0; j < 4; ++j)
#pragma unroll
            for (int reg = 0; reg < 4; ++reg) {
                int sg = s0 + w * 16 + lg * 4 + reg;
                int dg = d0 + j * 16 + lc;
                C1[(size_t)sg * D + dg] = acc[j][reg] + b1[dg];
            }
    }
}

// ---------------- main GEMM: 256x256 tile, 8 row-strip waves, A direct-from-global ----
__device__ __forceinline__ void gload16(const void* src, void* dst) {
    __builtin_amdgcn_global_load_lds((const __attribute__((address_space(1))) void*)src,
                                     (__attribute__((address_space(3))) void*)dst, 16, 0, 0);
}

__global__ __launch_bounds__(512, 2) void gemm_mfma(
    const float* __restrict__ feat, const ushort* __restrict__ w1tsw,
    const float* __restrict__ w2, const float* __restrict__ gterm,
    const float* __restrict__ C1, float* __restrict__ score) {
    __shared__ short sB[2][4][256][16];  // [buf][kchunk][row d][2 slots x 8] — 64 KB
    int t = threadIdx.x;
    // XCD-chunked bijective swizzle (512 blocks = 8 XCDs x 64): col-pairs share an XCD
    int id = (int)blockIdx.x;
    int lid = (id & 7) * 64 + (id >> 3);
    int rp = lid >> 1, cp = lid & 1;
    int row0 = rp << 8;  // 256 rows of B*S
    int d0 = cp << 8;    // 256 cols of D
    int b = row0 >> 9;

    const ushort* btile = w1tsw + (size_t)(cp * 32) * 16384;
    int wv = t >> 6, l = t & 63, lc = l & 15, lg = l >> 4;
    int wbase = (t & ~63);
    int hs = (lc >> 2) & 1;  // lane-uniform slot for all fragment rows
    int oh = hs * 8, ol = (hs ^ 1) * 8;

    // wave wv owns rows [wv*32, wv*32+32); lane A-fragment rows: wv*32 + i*16 + lc
    const float* aptr = feat + (size_t)(row0 + wv * 32 + lc) * D + lg * 8;

    f32x4 acc[2][16] = {};
    f32x4 av[2][2];

    // ---- prologue: A(ts=0) into regs, B(ts=0) -> LDS via DMA ----
    av[0][0] = *(const f32x4*)(aptr);
    av[0][1] = *(const f32x4*)(aptr + 4);
    av[1][0] = *(const f32x4*)(aptr + 16 * D);
    av[1][1] = *(const f32x4*)(aptr + 16 * D + 4);
#pragma unroll
    for (int q = 0; q < 4; ++q)
        gload16(btile + (size_t)(q * 512 + t) * 8,
                &sB[0][0][0][0] + (size_t)(q * 512 + wbase) * 8);
    __syncthreads();

    for (int ts = 0; ts < 16; ++ts) {
        int cur = ts & 1, nxt = cur ^ 1;
        f32x4 avn[2][2];
        if (ts < 15) {
            // issue next-tile loads early: A -> regs, B -> LDS (DMA)
            const float* ap = aptr + (ts + 1) * 32;
            avn[0][0] = *(const f32x4*)(ap);
            avn[0][1] = *(const f32x4*)(ap + 4);
            avn[1][0] = *(const f32x4*)(ap + 16 * D);
            avn[1][1] = *(const f32x4*)(ap + 16 * D + 4);
#pragma unroll
            for (int q = 0; q < 4; ++q)
                gload16(btile + (size_t)(ts + 1) * 16384 + (size_t)(q * 512 + t) * 8,
                        &sB[nxt][0][0][0] + (size_t)(q * 512 + wbase) * 8);
        }
        // ---- split current A regs into hi/lo fragments (bit-identical to staged path) ----
        bf16x8 ahf[2], alf[2];
#pragma unroll
        for (int i = 0; i < 2; ++i)
#pragma unroll
            for (int e = 0; e < 8; ++e) {
                unsigned p = splitf(av[i][e >> 2][e & 3]);
                ahf[i][e] = (short)(p & 0xFFFFu);
                alf[i][e] = (short)(p >> 16);
            }
        __builtin_amdgcn_s_setprio(1);
#pragma unroll
        for (int j = 0; j < 16; ++j) {
            const short* bp = &sB[cur][lg][j * 16 + lc][0];
            bf16x8 bh = *(const bf16x8*)(bp + oh);
            bf16x8 bl = *(const bf16x8*)(bp + ol);
#pragma unroll
            for (int i = 0; i < 2; ++i) {
                acc[i][j] = __builtin_amdgcn_mfma_f32_16x16x32_bf16(ahf[i], bh, acc[i][j], 0, 0, 0);
                acc[i][j] = __builtin_amdgcn_mfma_f32_16x16x32_bf16(ahf[i], bl, acc[i][j], 0, 0, 0);
                acc[i][j] = __builtin_amdgcn_mfma_f32_16x16x32_bf16(alf[i], bh, acc[i][j], 0, 0, 0);
            }
        }
        __builtin_amdgcn_s_setprio(0);
        if (ts < 15) {
            av[0][0] = avn[0][0]; av[0][1] = avn[0][1];
            av[1][0] = avn[1][0]; av[1][1] = avn[1][1];
        }
        __syncthreads();  // drains vmcnt (B DMA for nxt) before buffer swap
    }

    // ---- epilogue: + gterm + C1, ReLU, dot w2, reduce over d, atomic score ----
    float w2v[16], gt[16];
#pragma unroll
    for (int j = 0; j < 16; ++j) {
        int d = d0 + j * 16 + lc;
        w2v[j] = w2[d];
        gt[j] = gterm[b * D + d];
    }
#pragma unroll
    for (int i = 0; i < 2; ++i)
#pragma unroll
        for (int reg = 0; reg < 4; ++reg) {
            int srow = row0 + wv * 32 + i * 16 + lg * 4 + reg;
            int s = srow & 511;
            float part = 0.f;
#pragma unroll
            for (int j = 0; j < 16; ++j) {
                int d = d0 + j * 16 + lc;
                float z = acc[i][j][reg] + gt[j] + C1[(size_t)s * D + d];
                part += w2v[j] * fmaxf(z, 0.f);
            }
#pragma unroll
            for (int off = 8; off; off >>= 1) part += __shfl_down(part, off, 16);
            if (lc == 0) atomicAdd(&score[srow], part);
        }
}

// ---------------- per-batch top-10 + one-hot + gather ----------------
__global__ void topk_kernel(const float* __restrict__ score, const float* __restrict__ feat,
                            float* __restrict__ out_ind, float* __restrict__ out_sel) {
    __shared__ float work[512];
    __shared__ float wvv[8];
    __shared__ int wii[8];
    __shared__ int topi[TOPK];
    int b = blockIdx.x, t = threadIdx.x;
    work[t] = score[b * S + t];
    __syncthreads();
    for (int it = 0; it < TOPK; ++it) {
        float v = work[t];
        int i = t;
#pragma unroll
        for (int off = 32; off; off >>= 1) {
            float ov = __shfl_down(v, off);
            int oi = __shfl_down(i, off);
            if (ov > v || (ov == v && oi < i)) { v = ov; i = oi; }
        }
        if ((t & 63) == 0) { wvv[t >> 6] = v; wii[t >> 6] = i; }
        __syncthreads();
        if (t == 0) {
            float bv = wvv[0];
            int bi = wii[0];
            for (int w = 1; w < 8; ++w)
                if (wvv[w] > bv || (wvv[w] == bv && wii[w] < bi)) { bv = wvv[w]; bi = wii[w]; }
            topi[it] = bi;
            work[bi] = -INFINITY;
        }
        __syncthreads();
    }
    if (t == 0) {
        for (int a = 1; a < TOPK; ++a) {
            int key = topi[a];
            int c = a - 1;
            while (c >= 0 && topi[c] > key) { topi[c + 1] = topi[c]; --c; }
            topi[c + 1] = key;
        }
    }
    __syncthreads();
    // branchless one-hot + vectorized gather (threads 0..127, float4 lanes)
    if (t < 128) {
        float4* oi4 = (float4*)(out_ind + (size_t)b * TOPK * S);
        float4* os4 = (float4*)(out_sel + (size_t)b * TOPK * D);
        const float4* fb4 = (const float4*)(feat + (size_t)b * S * D);
#pragma unroll
        for (int k = 0; k < TOPK; ++k) {
            int idx = topi[k];
            float4 ohv;
            ohv.x = (4 * t + 0 == idx) ? 1.0f : 0.0f;
            ohv.y = (4 * t + 1 == idx) ? 1.0f : 0.0f;
            ohv.z = (4 * t + 2 == idx) ? 1.0f : 0.0f;
            ohv.w = (4 * t + 3 == idx) ? 1.0f : 0.0f;
            oi4[k * (S / 4) + t] = ohv;
            os4[k * (D / 4) + t] = fb4[(size_t)idx * (D / 4) + t];
        }
    }
}

extern "C" void kernel_launch(void* const* d_in, const int* in_sizes, int n_in,
                              void* d_out, int out_size, void* d_ws, size_t ws_size,
                              hipStream_t stream) {
    const float* x  = (const float*)d_in[0];
    const float* w1 = (const float*)d_in[1];
    const float* b1 = (const float*)d_in[2];
    const float* w2 = (const float*)d_in[3];
    // b2 (d_in[4]): uniform score shift, ranking-invariant -> dropped.

    float* out = (float*)d_out;
    float* out_ind = out;                              // [B,10,S]
    float* out_sel = out + (size_t)B * TOPK * S;       // [B,10,D]
    float* feat    = out + 2 * (size_t)B * TOPK * S;   // [B,S,D]

    float* ws      = (float*)d_ws;
    float* score   = ws;                        // [B*S]
    float* gterm   = ws + 65536;                // [B*D]
    float* g_part  = ws + 131072;               // [8][B][D]
    float* C1      = ws + 655360;               // [S*D]
    ushort* w1tsw  = (ushort*)(ws + 917504);    // [2][32][4][256][16] ushorts, slot-swizzled
    ushort* peh    = (ushort*)(ws + 1441792);   // [512][1024] bf16 (row-major)
    ushort* pel    = (ushort*)(ws + 1703936);

    fused_stage1<<<4672, 512, 0, stream>>>(x, feat, g_part, peh, pel, w1, w1tsw);
    fused_stage2<<<320, 256, 0, stream>>>(g_part, w1, gterm, score, peh, pel, w1tsw, b1, C1);
    gemm_mfma<<<512, 512, 0, stream>>>(feat, w1tsw, w2, gterm, C1, score);
    topk_kernel<<<B, 512, 0, stream>>>(score, feat, out_ind, out_sel);
}